// Round 17
// baseline (569.801 us; speedup 1.0000x reference)
//
#include <hip/hip_runtime.h>
#include <math.h>

#define D_MODEL 1024
#define NH      16
#define DH      64
#define S_LEN   2048
#define BATCH   4

typedef unsigned short u16;
typedef __attribute__((ext_vector_type(8))) short s8v;   // 8 bf16 (4 VGPRs)
typedef __attribute__((ext_vector_type(4))) float f4v;   // 4 f32 acc

#define MFMA(a, b, c) __builtin_amdgcn_mfma_f32_16x16x32_bf16((a), (b), (c), 0, 0, 0)

// async global->LDS DMA, 16B/lane: lds dest = uniform base + lane*16 (linear!)
#define GLOAD16(g, l)                                                        \
  __builtin_amdgcn_global_load_lds(                                          \
      (const __attribute__((address_space(1))) void*)(g),                    \
      (__attribute__((address_space(3))) void*)(l), 16, 0, 0)

__device__ inline u16 f2bf(float f) {                    // RNE
  unsigned u = __float_as_uint(f);
  u += 0x7fffu + ((u >> 16) & 1u);
  return (u16)(u >> 16);
}
__device__ inline float bf2f(u16 h) {
  return __uint_as_float(((unsigned)h) << 16);
}
__device__ inline u16 f2bf_trunc(float f) {              // lo-residual: trunc ok
  return (u16)(__float_as_uint(f) >> 16);
}
__device__ inline void split4(const float4 v, short4& h4, short4& l4) {
  u16 hx = f2bf(v.x), hy = f2bf(v.y), hz = f2bf(v.z), hw = f2bf(v.w);
  h4 = make_short4((short)hx, (short)hy, (short)hz, (short)hw);
  l4 = make_short4((short)f2bf_trunc(v.x - bf2f(hx)), (short)f2bf_trunc(v.y - bf2f(hy)),
                   (short)f2bf_trunc(v.z - bf2f(hz)), (short)f2bf_trunc(v.w - bf2f(hw)));
}

// ---------------------------------------------------------------------------
// RoPE table: tab[0:65536) = cos, tab[65536:131072) = sin, idx = s*32 + p
// ---------------------------------------------------------------------------
__global__ void rope_table_kernel(float* __restrict__ tab) {
  int i = blockIdx.x * 256 + threadIdx.x;
  if (i >= S_LEN * 32) return;
  int s = i >> 5;
  int p = i & 31;
  float invf = (float)pow(10000.0, -(double)p / 32.0);
  float ang = (float)s * invf;
  tab[i]         = cosf(ang);
  tab[65536 + i] = sinf(ang);
}

// ---------------------------------------------------------------------------
// fp32 -> bf16 hi/lo plane split (bandwidth-bound, one pass)
// ---------------------------------------------------------------------------
__global__ __launch_bounds__(256) void split_kernel(
    const float* __restrict__ src, u16* __restrict__ dh, u16* __restrict__ dl, int n4) {
  int i = blockIdx.x * 256 + threadIdx.x;
  if (i >= n4) return;
  float4 v = reinterpret_cast<const float4*>(src)[i];
  short4 h4, l4;
  split4(v, h4, l4);
  reinterpret_cast<short4*>(dh)[i] = h4;
  reinterpret_cast<short4*>(dl)[i] = l4;
}

// ---------------------------------------------------------------------------
// Split-bf16 MFMA GEMM v3: pre-split hi/lo planes, staging via
// global_load_lds DMA (no ds_writes, no staging regs — m97 pattern).
// BM=BN=128, BK=32, 256 thr = 4 waves (2x2), 64x64/wave, 3-MFMA split.
// MODE 0: fp32 store to C.   MODE 1: RoPE epilogue -> q/k planes + v fp32.
// ---------------------------------------------------------------------------
template <int MODE>
__global__ __launch_bounds__(256) void gemm3(
    const u16* __restrict__ Ah, const u16* __restrict__ Al,
    const u16* __restrict__ Bh, const u16* __restrict__ Bl,
    float* __restrict__ C,
    u16* __restrict__ qh, u16* __restrict__ ql,
    u16* __restrict__ kh, u16* __restrict__ kl,
    float* __restrict__ vw,
    const float* __restrict__ tab,
    int M, int N, int K)
{
  __shared__ u16 As[2][128][32];   // [plane][row][k] — LINEAR (gload_lds dest)
  __shared__ u16 Bs[2][128][32];

  const int tid  = threadIdx.x;
  const int lane = tid & 63;
  const int wv   = tid >> 6;
  const int wm = wv >> 1, wn = wv & 1;
  const int m0 = blockIdx.y * 128;
  const int n0 = blockIdx.x * 128;

  const int lr = lane & 15;
  const int lk = (lane >> 4) * 8;

  // staging geometry: wave wv owns rows [wv*32, wv*32+32); 2 issues of 16 rows.
  // lane i covers row +i/4, elements 8*(i&3)..+8 (matches DMA's base+lane*16B).
  const int gr = lane >> 2;          // 0..15
  const int gc = (lane & 3) * 8;     // 0,8,16,24

  f4v acc[4][4] = {};

  for (int k0 = 0; k0 < K; k0 += 32) {
    __syncthreads();                 // prev compute done reading LDS
#pragma unroll
    for (int j = 0; j < 2; ++j) {
      const int r0 = wv * 32 + j * 16;
      const size_t ga = (size_t)(m0 + r0 + gr) * K + k0 + gc;
      const size_t gb = (size_t)(n0 + r0 + gr) * K + k0 + gc;
      GLOAD16(Ah + ga, &As[0][r0][0]);
      GLOAD16(Al + ga, &As[1][r0][0]);
      GLOAD16(Bh + gb, &Bs[0][r0][0]);
      GLOAD16(Bl + gb, &Bs[1][r0][0]);
    }
    asm volatile("s_waitcnt vmcnt(0)" ::: "memory");
    __syncthreads();                 // tile staged

    s8v ah[4], al[4], bh[4], bl[4];
#pragma unroll
    for (int x = 0; x < 4; ++x) {
      ah[x] = *(const s8v*)&As[0][wm * 64 + x * 16 + lr][lk];
      al[x] = *(const s8v*)&As[1][wm * 64 + x * 16 + lr][lk];
      bh[x] = *(const s8v*)&Bs[0][wn * 64 + x * 16 + lr][lk];
      bl[x] = *(const s8v*)&Bs[1][wn * 64 + x * 16 + lr][lk];
    }
#pragma unroll
    for (int mf = 0; mf < 4; ++mf)
#pragma unroll
      for (int nf = 0; nf < 4; ++nf) {
        acc[mf][nf] = MFMA(ah[mf], bh[nf], acc[mf][nf]);
        acc[mf][nf] = MFMA(al[mf], bh[nf], acc[mf][nf]);
        acc[mf][nf] = MFMA(ah[mf], bl[nf], acc[mf][nf]);
      }
  }

  // epilogue — D layout: col = lane&15, row = (lane>>4)*4 + i
  if (MODE == 0) {
#pragma unroll
    for (int mf = 0; mf < 4; ++mf)
#pragma unroll
      for (int nf = 0; nf < 4; ++nf) {
        int c = n0 + wn * 64 + nf * 16 + lr;
#pragma unroll
        for (int i = 0; i < 4; ++i) {
          int m = m0 + wm * 64 + mf * 16 + (lane >> 4) * 4 + i;
          C[(size_t)m * N + c] = acc[mf][nf][i];
        }
      }
  } else {
#pragma unroll
    for (int nf = 0; nf < 4; ++nf) {
      int c = n0 + wn * 64 + nf * 16 + lr;
      int t = c >> 10;                    // 0=q 1=k 2=v
      int h = (c & 1023) >> 6;
      int d = c & 63;
#pragma unroll
      for (int mf = 0; mf < 4; ++mf)
#pragma unroll
        for (int i = 0; i < 4; ++i) {
          int m = m0 + wm * 64 + mf * 16 + (lane >> 4) * 4 + i;
          int b = m >> 11, s = m & 2047;
          float v  = acc[mf][nf][i];
          float pv = __shfl_xor(v, 1);    // partner column (c^1), same row
          size_t off = ((size_t)(b * NH + h) * S_LEN + s) * DH + d;
          if (t == 2) {
            vw[off] = v;
          } else {
            int p = d >> 1;
            float co = tab[s * 32 + p], si = tab[65536 + s * 32 + p];
            float res = ((d & 1) == 0) ? (v * co - pv * si)
                                       : (pv * si + v * co);
            u16 hi = f2bf(res);
            u16 lo = f2bf_trunc(res - bf2f(hi));
            ((t == 0) ? qh : kh)[off] = hi;
            ((t == 0) ? ql : kl)[off] = lo;
          }
        }
    }
  }
}

// ---------------------------------------------------------------------------
// V transpose: vw fp32 [bh][s][64] -> vth bf16 [bh][64][2048] (hi only)
// ---------------------------------------------------------------------------
__global__ __launch_bounds__(256) void vtrans_kernel(
    const float* __restrict__ vw, u16* __restrict__ vth)
{
  __shared__ float T[64][65];
  const int tid = threadIdx.x;
  const int st = blockIdx.x, bh = blockIdx.y;
  const int s0 = st * 64;
#pragma unroll
  for (int it = 0; it < 4; ++it) {
    int f = it * 256 + tid;
    int r = f >> 4, c4 = (f & 15) * 4;
    float4 v = *(const float4*)&vw[((size_t)bh * S_LEN + s0 + r) * DH + c4];
    T[r][c4 + 0] = v.x; T[r][c4 + 1] = v.y; T[r][c4 + 2] = v.z; T[r][c4 + 3] = v.w;
  }
  __syncthreads();
#pragma unroll
  for (int it = 0; it < 16; ++it) {
    int f = it * 256 + tid;
    int d = f >> 6, sc = f & 63;
    vth[((size_t)bh * DH + d) * S_LEN + s0 + sc] = f2bf(T[sc][d]);
  }
}

// ---------------------------------------------------------------------------
// Flash attention v4 (validated r15): PV pure bf16, LDS 37 KiB, T14 prefetch.
// ---------------------------------------------------------------------------
__global__ __launch_bounds__(256) void attn4_kernel(
    const u16* __restrict__ qhp, const u16* __restrict__ qlp,
    const u16* __restrict__ khp, const u16* __restrict__ klp,
    const u16* __restrict__ vthp,
    u16* __restrict__ ohp, u16* __restrict__ olp)
{
  __shared__ u16 Kh[64][72], Kl[64][72];   // K tile [s][d], pad 64->72
  __shared__ u16 Vh[64][72];               // V^T tile [d][s]
  __shared__ u16 Ph[4][16][72];            // wave-private P (bf16)

  const int tid  = threadIdx.x;
  const int lane = tid & 63;
  const int w    = tid >> 6;
  const int bid = blockIdx.x;
  const int swz = (bid & 7) * 256 + (bid >> 3);  // XCD-chunked, bijective
  const int bh  = swz >> 5;
  const int qt  = 31 - (swz & 31);               // work-descending
  const int q0  = qt * 64;

  const int lr = lane & 15;
  const int lk = (lane >> 4) * 8;
  const int rg = (lane >> 4) * 4;

  const size_t kvbase = (size_t)bh * S_LEN * DH;   // [bh][s][64]
  const size_t vtbase = (size_t)bh * DH * S_LEN;   // [bh][64][2048]

  const int sr  = tid >> 2;
  const int sc0 = (tid & 3) * 16;

  const u16* qrow_h = qhp + kvbase + (size_t)(q0 + w * 16 + lr) * DH;
  const u16* qrow_l = qlp + kvbase + (size_t)(q0 + w * 16 + lr) * DH;
  s8v qfh[2], qfl[2];
#pragma unroll
  for (int c = 0; c < 2; ++c) {
    qfh[c] = *(const s8v*)(qrow_h + c * 32 + lk);
    qfl[c] = *(const s8v*)(qrow_l + c * 32 + lk);
  }

  float m_run[4] = {-3.0e38f, -3.0e38f, -3.0e38f, -3.0e38f};
  float l_run[4] = {0.f, 0.f, 0.f, 0.f};
  f4v o[4] = {};

  s8v rkh[2], rkl[2], rvh[2];
  {
    const size_t koff = kvbase + (size_t)sr * DH + sc0;
    const size_t voff = vtbase + (size_t)sr * S_LEN + sc0;
    rkh[0] = *(const s8v*)(khp + koff);   rkh[1] = *(const s8v*)(khp + koff + 8);
    rkl[0] = *(const s8v*)(klp + koff);   rkl[1] = *(const s8v*)(klp + koff + 8);
    rvh[0] = *(const s8v*)(vthp + voff);  rvh[1] = *(const s8v*)(vthp + voff + 8);
  }

  for (int kt = 0; kt <= qt; ++kt) {
    __syncthreads();
    *(s8v*)&Kh[sr][sc0] = rkh[0];  *(s8v*)&Kh[sr][sc0 + 8] = rkh[1];
    *(s8v*)&Kl[sr][sc0] = rkl[0];  *(s8v*)&Kl[sr][sc0 + 8] = rkl[1];
    *(s8v*)&Vh[sr][sc0] = rvh[0];  *(s8v*)&Vh[sr][sc0 + 8] = rvh[1];
    __syncthreads();

    if (kt < qt) {                        // prefetch next tile under compute
      const int kn = (kt + 1) * 64;
      const size_t koff = kvbase + (size_t)(kn + sr) * DH + sc0;
      const size_t voff = vtbase + (size_t)sr * S_LEN + kn + sc0;
      rkh[0] = *(const s8v*)(khp + koff);   rkh[1] = *(const s8v*)(khp + koff + 8);
      rkl[0] = *(const s8v*)(klp + koff);   rkl[1] = *(const s8v*)(klp + koff + 8);
      rvh[0] = *(const s8v*)(vthp + voff);  rvh[1] = *(const s8v*)(vthp + voff + 8);
    }

    // ---- S = Q K^T (3-MFMA split) ----
    f4v sf[4] = {};
#pragma unroll
    for (int f = 0; f < 4; ++f)
#pragma unroll
      for (int c = 0; c < 2; ++c) {
        s8v kbh = *(const s8v*)&Kh[f * 16 + lr][c * 32 + lk];
        s8v kbl = *(const s8v*)&Kl[f * 16 + lr][c * 32 + lk];
        sf[f] = MFMA(qfh[c], kbh, sf[f]);
        sf[f] = MFMA(qfl[c], kbh, sf[f]);
        sf[f] = MFMA(qfh[c], kbl, sf[f]);
      }

    // ---- scale + causal mask + online softmax ----
    const bool diag = (kt == qt);
    float p[4][4];
    float sc[4][4];
#pragma unroll
    for (int f = 0; f < 4; ++f)
#pragma unroll
      for (int i = 0; i < 4; ++i) {
        float v = sf[f][i] * 0.125f;
        if (diag) {
          int col = f * 16 + lr;
          int row = w * 16 + rg + i;
          if (col > row) v = -3.0e38f;
        }
        sc[f][i] = v;
      }
#pragma unroll
    for (int i = 0; i < 4; ++i) {
      float mx = fmaxf(fmaxf(sc[0][i], sc[1][i]), fmaxf(sc[2][i], sc[3][i]));
#pragma unroll
      for (int off = 1; off < 16; off <<= 1) mx = fmaxf(mx, __shfl_xor(mx, off));
      float mnew  = fmaxf(m_run[i], mx);
      float alpha = __expf(m_run[i] - mnew);
      float rs = 0.f;
#pragma unroll
      for (int f = 0; f < 4; ++f) { p[f][i] = __expf(sc[f][i] - mnew); rs += p[f][i]; }
#pragma unroll
      for (int off = 1; off < 16; off <<= 1) rs += __shfl_xor(rs, off);
      l_run[i] = l_run[i] * alpha + rs;
      m_run[i] = mnew;
#pragma unroll
      for (int f2 = 0; f2 < 4; ++f2) o[f2][i] *= alpha;
    }

    // ---- P (bf16) to wave-private LDS ----
#pragma unroll
    for (int f = 0; f < 4; ++f)
#pragma unroll
      for (int i = 0; i < 4; ++i)
        Ph[w][rg + i][f * 16 + lr] = f2bf(p[f][i]);

    // ---- O += P V, pure bf16 ----
#pragma unroll
    for (int c = 0; c < 2; ++c) {
      s8v pah = *(const s8v*)&Ph[w][lr][c * 32 + lk];
#pragma unroll
      for (int f2 = 0; f2 < 4; ++f2) {
        s8v vbh = *(const s8v*)&Vh[f2 * 16 + lr][c * 32 + lk];
        o[f2] = MFMA(pah, vbh, o[f2]);
      }
    }
  }

  // ---- epilogue: /l, write hi/lo planes [b][s][h*64+d] ----
  const int b = bh >> 4, h = bh & 15;
#pragma unroll
  for (int i = 0; i < 4; ++i) {
    int s = q0 + w * 16 + rg + i;
    float inv = 1.0f / l_run[i];
#pragma unroll
    for (int f2 = 0; f2 < 4; ++f2) {
      int d = f2 * 16 + lr;
      float val = o[f2][i] * inv;
      size_t off = ((size_t)(b * S_LEN + s)) * D_MODEL + h * DH + d;
      u16 hi = f2bf(val);
      ohp[off] = hi;
      olp[off] = f2bf_trunc(val - bf2f(hi));
    }
  }
}

// ---------------------------------------------------------------------------
extern "C" void kernel_launch(void* const* d_in, const int* in_sizes, int n_in,
                              void* d_out, int out_size, void* d_ws, size_t ws_size,
                              hipStream_t stream) {
  const float* x     = (const float*)d_in[0];   // [8192,1024]
  const float* w_qkv = (const float*)d_in[1];   // [3072,1024]
  const float* w_out = (const float*)d_in[2];   // [1024,1024]
  float* out = (float*)d_out;

  const size_t NQ = (size_t)BATCH * NH * S_LEN * DH;   // 8388608 (= M*D_MODEL)
  const size_t NWQ = (size_t)3 * D_MODEL * D_MODEL;    // 3145728
  const size_t NWO = (size_t)D_MODEL * D_MODEL;        // 1048576

  float* ws  = (float*)d_ws;
  float* tab = ws;                          // 131072 f32
  float* vw  = ws + 131072;                 // NQ f32 (v, dead after vtrans)
  u16* u   = (u16*)(vw + NQ);
  u16* xh  = u;  u += NQ;                   // reused as oh after gemm<1>
  u16* xl  = u;  u += NQ;                   // reused as ol
  u16* wqh = u;  u += NWQ;
  u16* wql = u;  u += NWQ;
  u16* woh = u;  u += NWO;
  u16* wol = u;  u += NWO;
  u16* qh  = u;  u += NQ;
  u16* ql  = u;  u += NQ;
  u16* kh  = u;  u += NQ;
  u16* kl  = u;  u += NQ;
  u16* vth = u;  u += NQ;
  // total ~169 MB

  const int M = BATCH * S_LEN;   // 8192

  rope_table_kernel<<<(S_LEN * 32 + 255) / 256, 256, 0, stream>>>(tab);

  split_kernel<<<(int)(NQ / 4 + 255) / 256, 256, 0, stream>>>(x, xh, xl, (int)(NQ / 4));
  split_kernel<<<(int)(NWQ / 4 + 255) / 256, 256, 0, stream>>>(w_qkv, wqh, wql, (int)(NWQ / 4));
  split_kernel<<<(int)(NWO / 4 + 255) / 256, 256, 0, stream>>>(w_out, woh, wol, (int)(NWO / 4));

  gemm3<1><<<dim3(3 * D_MODEL / 128, M / 128), 256, 0, stream>>>(
      xh, xl, wqh, wql, nullptr, qh, ql, kh, kl, vw, tab, M, 3 * D_MODEL, D_MODEL);

  vtrans_kernel<<<dim3(S_LEN / 64, BATCH * NH), 256, 0, stream>>>(vw, vth);

  u16* oh = xh;   // x planes dead after QKV gemm
  u16* ol = xl;
  attn4_kernel<<<dim3(S_LEN / 64 * BATCH * NH), 256, 0, stream>>>(
      qh, ql, kh, kl, vth, oh, ol);

  gemm3<0><<<dim3(D_MODEL / 128, M / 128), 256, 0, stream>>>(
      oh, ol, woh, wol, out, nullptr, nullptr, nullptr, nullptr, nullptr, tab,
      M, D_MODEL, D_MODEL);
}